// Round 1
// baseline (1718.028 us; speedup 1.0000x reference)
//
#include <hip/hip_runtime.h>
#include <math.h>

// Problem constants
#define RTOT   196608   // B*T*N rows
#define NNODE  1024
#define DDIM   128
#define NBT    192      // B*T
#define NM     64
#define NTOPK  16

// ---------------- prep kernels ----------------
__global__ __launch_bounds__(256) void pos_kernel(
    const float* __restrict__ eigvec, const float* __restrict__ eigval,
    float* __restrict__ pos) {
  int i = blockIdx.x * 256 + threadIdx.x;      // < 1024*128
  int d = i >> 10, n = i & 1023;
  pos[n * 128 + d] = eigvec[d * 1024 + n] * eigval[d];
}

__global__ __launch_bounds__(256) void embT_kernel(
    const float* __restrict__ emb, float* __restrict__ embT) {
  int i = blockIdx.x * 256 + threadIdx.x;      // < 64*256
  int m = i >> 8, k = i & 255;
  embT[k * 64 + m] = emb[i];
}

// ---------------- generic 128-row-tile fp32 GEMM ----------------
// out[r][c] = act( sum_k Aeff[r][k] * W[k][c] (+bias) (+resid) )
// Aeff[r][k] = (A[r][k] (+pos) ) * (1/(cnt[r]+1e-14) if SCALECNT)
// K = 64*KCHUNKS; chunks with kt>=128 read from A2 (concat(Q,K) case).
template<int NCOL, int KCHUNKS, int ADDPOS, int SCALECNT, int RESID_XPOS,
         int RESID_PTR, int RELU, int HASBIAS>
__global__ __launch_bounds__(256, 2) void gemm_k(
    const float* __restrict__ A1, const float* __restrict__ A2,
    const float* __restrict__ W, const float* __restrict__ bias,
    const float* __restrict__ pos, const float* __restrict__ xres,
    const float* __restrict__ resid, const int* __restrict__ cnt,
    float* __restrict__ out) {
  __shared__ float As[128 * 64];          // [m][k], 32 KB
  __shared__ float Ws[64 * NCOL];         // [k][c], 32/16 KB
  constexpr int JW = (NCOL == 128) ? 2 : 1;
  const int tid = threadIdx.x;
  const int tx = tid & 15, ty = tid >> 4;
  const int row0 = blockIdx.x * 128;

  float acc[8][4 * JW];
#pragma unroll
  for (int i = 0; i < 8; ++i)
#pragma unroll
    for (int j = 0; j < 4 * JW; ++j) acc[i][j] = 0.f;

  for (int kc = 0; kc < KCHUNKS; ++kc) {
    const int kt = kc * 64;
    const float* __restrict__ Asrc = (kt < 128) ? A1 : A2;
    const int kbase = kt & 127;
    // load A tile: 128 rows x 64 cols (2048 float4, 8 per thread)
#pragma unroll
    for (int i = 0; i < 8; ++i) {
      int f = tid + 256 * i;
      int m = f >> 4;
      int k4 = (f & 15) << 2;
      int r = row0 + m;
      float4 a = *(const float4*)&Asrc[(size_t)r * 128 + kbase + k4];
      if constexpr (ADDPOS) {
        float4 p = *(const float4*)&pos[(r & 1023) * 128 + kbase + k4];
        a.x += p.x; a.y += p.y; a.z += p.z; a.w += p.w;
      }
      if constexpr (SCALECNT) {
        float s = 1.0f / ((float)cnt[r] + 1e-14f);
        a.x *= s; a.y *= s; a.z *= s; a.w *= s;
      }
      *(float4*)&As[m * 64 + k4] = a;
    }
    // load W tile: 64 x NCOL
#pragma unroll
    for (int i = 0; i < NCOL / 16; ++i) {
      int f = tid + 256 * i;
      int kk = f / (NCOL / 4);
      int c4 = (f % (NCOL / 4)) << 2;
      *(float4*)&Ws[kk * NCOL + c4] =
          *(const float4*)&W[(size_t)(kt + kk) * NCOL + c4];
    }
    __syncthreads();
    for (int k4 = 0; k4 < 64; k4 += 4) {
      float a[8][4];
#pragma unroll
      for (int i = 0; i < 8; ++i)
        *(float4*)&a[i][0] = *(const float4*)&As[(ty * 8 + i) * 64 + k4];
#pragma unroll
      for (int kk = 0; kk < 4; ++kk) {
        float4 w0 = *(const float4*)&Ws[(k4 + kk) * NCOL + tx * 4];
        float4 w1;
        if constexpr (JW == 2)
          w1 = *(const float4*)&Ws[(k4 + kk) * NCOL + 64 + tx * 4];
#pragma unroll
        for (int i = 0; i < 8; ++i) {
          float av = a[i][kk];
          acc[i][0] = fmaf(av, w0.x, acc[i][0]);
          acc[i][1] = fmaf(av, w0.y, acc[i][1]);
          acc[i][2] = fmaf(av, w0.z, acc[i][2]);
          acc[i][3] = fmaf(av, w0.w, acc[i][3]);
          if constexpr (JW == 2) {
            acc[i][4] = fmaf(av, w1.x, acc[i][4]);
            acc[i][5] = fmaf(av, w1.y, acc[i][5]);
            acc[i][6] = fmaf(av, w1.z, acc[i][6]);
            acc[i][7] = fmaf(av, w1.w, acc[i][7]);
          }
        }
      }
    }
    __syncthreads();
  }
  // epilogue
  float4 b0 = make_float4(0.f, 0.f, 0.f, 0.f);
  float4 b1 = make_float4(0.f, 0.f, 0.f, 0.f);
  if constexpr (HASBIAS) {
    b0 = *(const float4*)&bias[tx * 4];
    if constexpr (JW == 2) b1 = *(const float4*)&bias[64 + tx * 4];
  }
#pragma unroll
  for (int i = 0; i < 8; ++i) {
    const int r = row0 + ty * 8 + i;
    {
      const int c = tx * 4;
      float4 o = make_float4(acc[i][0] + b0.x, acc[i][1] + b0.y,
                             acc[i][2] + b0.z, acc[i][3] + b0.w);
      if constexpr (RESID_XPOS) {
        float4 xv = *(const float4*)&xres[(size_t)r * 128 + c];
        float4 pv = *(const float4*)&pos[(r & 1023) * 128 + c];
        o.x += xv.x + pv.x; o.y += xv.y + pv.y;
        o.z += xv.z + pv.z; o.w += xv.w + pv.w;
      }
      if constexpr (RESID_PTR) {
        float4 rv = *(const float4*)&resid[(size_t)r * 128 + c];
        o.x += rv.x; o.y += rv.y; o.z += rv.z; o.w += rv.w;
      }
      if constexpr (RELU) {
        o.x = fmaxf(o.x, 0.f); o.y = fmaxf(o.y, 0.f);
        o.z = fmaxf(o.z, 0.f); o.w = fmaxf(o.w, 0.f);
      }
      *(float4*)&out[(size_t)r * NCOL + c] = o;
    }
    if constexpr (JW == 2) {
      const int c = 64 + tx * 4;
      float4 o = make_float4(acc[i][4] + b1.x, acc[i][5] + b1.y,
                             acc[i][6] + b1.z, acc[i][7] + b1.w);
      if constexpr (RESID_XPOS) {
        float4 xv = *(const float4*)&xres[(size_t)r * 128 + c];
        float4 pv = *(const float4*)&pos[(r & 1023) * 128 + c];
        o.x += xv.x + pv.x; o.y += xv.y + pv.y;
        o.z += xv.z + pv.z; o.w += xv.w + pv.w;
      }
      if constexpr (RESID_PTR) {
        float4 rv = *(const float4*)&resid[(size_t)r * 128 + c];
        o.x += rv.x; o.y += rv.y; o.z += rv.z; o.w += rv.w;
      }
      if constexpr (RELU) {
        o.x = fmaxf(o.x, 0.f); o.y = fmaxf(o.y, 0.f);
        o.z = fmaxf(o.z, 0.f); o.w = fmaxf(o.w, 0.f);
      }
      *(float4*)&out[(size_t)r * NCOL + c] = o;
    }
  }
}

// ---------------- top-16 per (bt, m) over 1024 scores ----------------
// S: [RTOT][64] row-major (scores, col = m). block = (bt, mg of 8 m's)
__global__ __launch_bounds__(256) void topk_kernel(
    const float* __restrict__ S, int* __restrict__ idx_out) {
  __shared__ float sc[8 * 1024];   // 32 KB
  const int tid = threadIdx.x;
  const int bt = blockIdx.x >> 3, mg = blockIdx.x & 7;
#pragma unroll
  for (int u = 0; u < 8; ++u) {
    int f = tid + 256 * u;         // < 2048
    int n = f >> 1, half = f & 1;
    float4 v = *(const float4*)&S[((size_t)bt * 1024 + n) * 64 + mg * 8 + half * 4];
    sc[(half * 4 + 0) * 1024 + n] = v.x;
    sc[(half * 4 + 1) * 1024 + n] = v.y;
    sc[(half * 4 + 2) * 1024 + n] = v.z;
    sc[(half * 4 + 3) * 1024 + n] = v.w;
  }
  __syncthreads();
  const int lane = tid & 63, w = tid >> 6;
  for (int ml = w * 2; ml < w * 2 + 2; ++ml) {
    float v[16];
#pragma unroll
    for (int q = 0; q < 4; ++q) {
      float4 t = *(const float4*)&sc[ml * 1024 + lane * 16 + q * 4];
      v[q * 4 + 0] = t.x; v[q * 4 + 1] = t.y;
      v[q * 4 + 2] = t.z; v[q * 4 + 3] = t.w;
    }
    const int outbase = (bt * 64 + mg * 8 + ml) << 4;
    for (int it = 0; it < 16; ++it) {
      float mv = v[0]; int li = 0;
#pragma unroll
      for (int u = 1; u < 16; ++u) {
        if (v[u] > mv) { mv = v[u]; li = u; }
      }
      int mi = (lane << 4) + li;
#pragma unroll
      for (int off = 1; off < 64; off <<= 1) {
        float ov = __shfl_xor(mv, off);
        int oi = __shfl_xor(mi, off);
        if (ov > mv || (ov == mv && oi < mi)) { mv = ov; mi = oi; }
      }
      // remove winner (tie-break matches jax: larger value, then smaller idx)
      bool mine = (mi >> 4) == lane;
      int rm = mi & 15;
#pragma unroll
      for (int u = 0; u < 16; ++u)
        if (mine && rm == u) v[u] = -3.402823466e38f;
      if (lane == 0) idx_out[outbase + it] = mi;
    }
  }
}

// ---------------- 16x16 attention + scatter-add ----------------
__global__ __launch_bounds__(256) void attn_scatter(
    const float* __restrict__ Q, const float* __restrict__ K,
    const float* __restrict__ V, const int* __restrict__ idx,
    float* __restrict__ dict, int* __restrict__ cnt) {
  __shared__ float sQ[16 * 132], sK[16 * 132], sV[16 * 132];
  __shared__ float sP[16 * 16];
  __shared__ int sidx[16];
  const int tid = threadIdx.x;
  const int bt = blockIdx.x >> 6, m = blockIdx.x & 63;
  if (tid < 16) sidx[tid] = idx[((bt * 64 + m) << 4) + tid];
  __syncthreads();
  const size_t base = (size_t)bt * 1024 * 128;
  // gather 3 x 16 rows of 128
#pragma unroll
  for (int u = 0; u < 6; ++u) {
    int f = tid + 256 * u;         // < 1536
    int mat = f >> 9;
    int r = (f >> 5) & 15;
    int c4 = (f & 31) << 2;
    const float* src = (mat == 0) ? Q : (mat == 1) ? K : V;
    float* dst = (mat == 0) ? sQ : (mat == 1) ? sK : sV;
    *(float4*)&dst[r * 132 + c4] =
        *(const float4*)&src[base + (size_t)sidx[r] * 128 + c4];
  }
  __syncthreads();
  // scores S[k][j] and softmax over j (16-lane groups)
  const int kk = tid >> 4, jj = tid & 15;
  float s = 0.f;
#pragma unroll
  for (int c4 = 0; c4 < 128; c4 += 4) {
    float4 q = *(const float4*)&sQ[kk * 132 + c4];
    float4 kv = *(const float4*)&sK[jj * 132 + c4];
    s = fmaf(q.x, kv.x, s); s = fmaf(q.y, kv.y, s);
    s = fmaf(q.z, kv.z, s); s = fmaf(q.w, kv.w, s);
  }
  s *= 0.08838834764831845f;       // 1/sqrt(128)
  float mx = s;
#pragma unroll
  for (int off = 8; off >= 1; off >>= 1) mx = fmaxf(mx, __shfl_xor(mx, off, 16));
  float e = expf(s - mx);
  float sum = e;
#pragma unroll
  for (int off = 8; off >= 1; off >>= 1) sum += __shfl_xor(sum, off, 16);
  sP[kk * 16 + jj] = e / sum;
  __syncthreads();
  // PV: row kk, col-group dc (8 cols each)
  const int dc = tid & 15;
  const int d0 = dc * 8;
  float o[8] = {0.f, 0.f, 0.f, 0.f, 0.f, 0.f, 0.f, 0.f};
#pragma unroll
  for (int j = 0; j < 16; ++j) {
    float p = sP[kk * 16 + j];
    float4 v0 = *(const float4*)&sV[j * 132 + d0];
    float4 v1 = *(const float4*)&sV[j * 132 + d0 + 4];
    o[0] = fmaf(p, v0.x, o[0]); o[1] = fmaf(p, v0.y, o[1]);
    o[2] = fmaf(p, v0.z, o[2]); o[3] = fmaf(p, v0.w, o[3]);
    o[4] = fmaf(p, v1.x, o[4]); o[5] = fmaf(p, v1.y, o[5]);
    o[6] = fmaf(p, v1.z, o[6]); o[7] = fmaf(p, v1.w, o[7]);
  }
  float* drow = dict + base + (size_t)sidx[kk] * 128 + d0;
#pragma unroll
  for (int u = 0; u < 8; ++u) atomicAdd(&drow[u], o[u]);
  if (tid < 16) atomicAdd(&cnt[bt * 1024 + sidx[tid]], 1);
}

// ---------------- LayerNorm over D=128, one wave per row ----------------
__global__ __launch_bounds__(256) void ln_kernel(
    const float* __restrict__ in, float* __restrict__ out) {
  const int lane = threadIdx.x & 63;
  const int row = blockIdx.x * 4 + (threadIdx.x >> 6);
  const float* p = in + (size_t)row * 128;
  float2 v = *(const float2*)&p[lane * 2];
  float s = v.x + v.y;
#pragma unroll
  for (int off = 32; off >= 1; off >>= 1) s += __shfl_xor(s, off);
  float mu = s * (1.f / 128.f);
  float dx = v.x - mu, dy = v.y - mu;
  float q = dx * dx + dy * dy;
#pragma unroll
  for (int off = 32; off >= 1; off >>= 1) q += __shfl_xor(q, off);
  float rstd = rsqrtf(q * (1.f / 128.f) + 1e-5f);
  float2 o = make_float2(dx * rstd, dy * rstd);
  *(float2*)&out[(size_t)row * 128 + lane * 2] = o;
}

// ---------------- launch ----------------
extern "C" void kernel_launch(void* const* d_in, const int* in_sizes, int n_in,
                              void* d_out, int out_size, void* d_ws, size_t ws_size,
                              hipStream_t stream) {
  const float* x      = (const float*)d_in[0];
  const float* eigvec = (const float*)d_in[1];
  const float* eigval = (const float*)d_in[2];
  const float* Wq     = (const float*)d_in[3];
  const float* bq     = (const float*)d_in[4];
  const float* Wk     = (const float*)d_in[5];
  const float* bk     = (const float*)d_in[6];
  const float* Wv     = (const float*)d_in[7];
  const float* bv     = (const float*)d_in[8];
  const float* Wo     = (const float*)d_in[9];
  const float* bo     = (const float*)d_in[10];
  const float* nemb   = (const float*)d_in[11];
  const float* ffW1   = (const float*)d_in[12];
  const float* ffb1   = (const float*)d_in[13];
  const float* ffW2   = (const float*)d_in[14];
  const float* ffb2   = (const float*)d_in[15];
  float* outp = (float*)d_out;

  char* ws = (char*)d_ws;
  const size_t SZ_MAT = (size_t)RTOT * 128 * 4;    // 100,663,296 B
  float* pos  = (float*)(ws + 0);                  // 512 KB
  float* embT = (float*)(ws + 524288);             // 64 KB
  int*   idxp = (int*)  (ws + 589824);             // 768 KB
  int*   cntp = (int*)  (ws + 1376256);            // 768 KB
  float* bufK = (float*)(ws + 2162688);
  float* bufV = (float*)(ws + 2162688 + SZ_MAT);
  float* bufD = (float*)(ws + 2162688 + 2 * SZ_MAT);
  float* Qbuf = outp;   // Q lives in d_out until the final LN

  pos_kernel<<<512, 256, 0, stream>>>(eigvec, eigval, pos);
  embT_kernel<<<64, 256, 0, stream>>>(nemb, embT);

  // Q, K, V = (x + pos) @ W + b
  gemm_k<128, 2, 1, 0, 0, 0, 0, 1><<<1536, 256, 0, stream>>>(
      x, nullptr, Wq, bq, pos, nullptr, nullptr, nullptr, Qbuf);
  gemm_k<128, 2, 1, 0, 0, 0, 0, 1><<<1536, 256, 0, stream>>>(
      x, nullptr, Wk, bk, pos, nullptr, nullptr, nullptr, bufK);
  gemm_k<128, 2, 1, 0, 0, 0, 0, 1><<<1536, 256, 0, stream>>>(
      x, nullptr, Wv, bv, pos, nullptr, nullptr, nullptr, bufV);

  // scores[n][m] = concat(Q,K)[n] . node_emb[m]  (softmax skipped: monotone)
  gemm_k<64, 4, 0, 0, 0, 0, 0, 0><<<1536, 256, 0, stream>>>(
      Qbuf, bufK, embT, nullptr, nullptr, nullptr, nullptr, nullptr, bufD);
  topk_kernel<<<1536, 256, 0, stream>>>(bufD, idxp);

  hipMemsetAsync(bufD, 0, SZ_MAT, stream);
  hipMemsetAsync(cntp, 0, (size_t)RTOT * 4, stream);
  attn_scatter<<<12288, 256, 0, stream>>>(Qbuf, bufK, bufV, idxp, bufD, cntp);

  // value = (dict/cnt) @ Wo + bo + (x + pos); then LN
  gemm_k<128, 2, 0, 1, 1, 0, 0, 1><<<1536, 256, 0, stream>>>(
      bufD, nullptr, Wo, bo, pos, x, nullptr, cntp, bufK);
  ln_kernel<<<49152, 256, 0, stream>>>(bufK, bufV);   // bufV = vln

  // FFN
  gemm_k<128, 2, 0, 0, 0, 0, 1, 1><<<1536, 256, 0, stream>>>(
      bufV, nullptr, ffW1, ffb1, nullptr, nullptr, nullptr, nullptr, bufD);
  gemm_k<128, 2, 0, 0, 0, 1, 0, 1><<<1536, 256, 0, stream>>>(
      bufD, nullptr, ffW2, ffb2, nullptr, nullptr, bufV, nullptr, bufK);
  ln_kernel<<<49152, 256, 0, stream>>>(bufK, outp);
}

// Round 2
// 1102.320 us; speedup vs baseline: 1.5586x; 1.5586x over previous
//
#include <hip/hip_runtime.h>
#include <math.h>

// Problem constants
#define RTOT   196608   // B*T*N rows
#define NNODE  1024
#define DDIM   128
#define NBT    192      // B*T
#define NM     64
#define NTOPK  16

// ---------------- prep kernels ----------------
__global__ __launch_bounds__(256) void pos_kernel(
    const float* __restrict__ eigvec, const float* __restrict__ eigval,
    float* __restrict__ pos) {
  int i = blockIdx.x * 256 + threadIdx.x;      // < 1024*128
  int d = i >> 10, n = i & 1023;
  pos[n * 128 + d] = eigvec[d * 1024 + n] * eigval[d];
}

__global__ __launch_bounds__(256) void embT_kernel(
    const float* __restrict__ emb, float* __restrict__ embT) {
  int i = blockIdx.x * 256 + threadIdx.x;      // < 64*256
  int m = i >> 8, k = i & 255;
  embT[k * 64 + m] = emb[i];
}

// ---------------- generic 128-row-tile fp32 GEMM ----------------
// out[r][c] = act( sum_k Aeff[r][k] * W[k][c] (+bias) (+resid) )
// K = 64*KCHUNKS; chunks with kt>=128 read from A2 (concat(Q,K) case).
template<int NCOL, int KCHUNKS, int ADDPOS, int RESID_XPOS,
         int RESID_PTR, int RELU, int HASBIAS>
__global__ __launch_bounds__(256, 2) void gemm_k(
    const float* __restrict__ A1, const float* __restrict__ A2,
    const float* __restrict__ W, const float* __restrict__ bias,
    const float* __restrict__ pos, const float* __restrict__ xres,
    const float* __restrict__ resid, float* __restrict__ out) {
  __shared__ float As[128 * 64];          // [m][k], 32 KB
  __shared__ float Ws[64 * NCOL];         // [k][c], 32/16 KB
  constexpr int JW = (NCOL == 128) ? 2 : 1;
  const int tid = threadIdx.x;
  const int tx = tid & 15, ty = tid >> 4;
  const int row0 = blockIdx.x * 128;

  float acc[8][4 * JW];
#pragma unroll
  for (int i = 0; i < 8; ++i)
#pragma unroll
    for (int j = 0; j < 4 * JW; ++j) acc[i][j] = 0.f;

  for (int kc = 0; kc < KCHUNKS; ++kc) {
    const int kt = kc * 64;
    const float* __restrict__ Asrc = (kt < 128) ? A1 : A2;
    const int kbase = kt & 127;
    // load A tile: 128 rows x 64 cols (2048 float4, 8 per thread)
#pragma unroll
    for (int i = 0; i < 8; ++i) {
      int f = tid + 256 * i;
      int m = f >> 4;
      int k4 = (f & 15) << 2;
      int r = row0 + m;
      float4 a = *(const float4*)&Asrc[(size_t)r * 128 + kbase + k4];
      if constexpr (ADDPOS) {
        float4 p = *(const float4*)&pos[(r & 1023) * 128 + kbase + k4];
        a.x += p.x; a.y += p.y; a.z += p.z; a.w += p.w;
      }
      *(float4*)&As[m * 64 + k4] = a;
    }
    // load W tile: 64 x NCOL
#pragma unroll
    for (int i = 0; i < NCOL / 16; ++i) {
      int f = tid + 256 * i;
      int kk = f / (NCOL / 4);
      int c4 = (f % (NCOL / 4)) << 2;
      *(float4*)&Ws[kk * NCOL + c4] =
          *(const float4*)&W[(size_t)(kt + kk) * NCOL + c4];
    }
    __syncthreads();
    for (int k4 = 0; k4 < 64; k4 += 4) {
      float a[8][4];
#pragma unroll
      for (int i = 0; i < 8; ++i)
        *(float4*)&a[i][0] = *(const float4*)&As[(ty * 8 + i) * 64 + k4];
#pragma unroll
      for (int kk = 0; kk < 4; ++kk) {
        float4 w0 = *(const float4*)&Ws[(k4 + kk) * NCOL + tx * 4];
        float4 w1;
        if constexpr (JW == 2)
          w1 = *(const float4*)&Ws[(k4 + kk) * NCOL + 64 + tx * 4];
#pragma unroll
        for (int i = 0; i < 8; ++i) {
          float av = a[i][kk];
          acc[i][0] = fmaf(av, w0.x, acc[i][0]);
          acc[i][1] = fmaf(av, w0.y, acc[i][1]);
          acc[i][2] = fmaf(av, w0.z, acc[i][2]);
          acc[i][3] = fmaf(av, w0.w, acc[i][3]);
          if constexpr (JW == 2) {
            acc[i][4] = fmaf(av, w1.x, acc[i][4]);
            acc[i][5] = fmaf(av, w1.y, acc[i][5]);
            acc[i][6] = fmaf(av, w1.z, acc[i][6]);
            acc[i][7] = fmaf(av, w1.w, acc[i][7]);
          }
        }
      }
    }
    __syncthreads();
  }
  // epilogue
  float4 b0 = make_float4(0.f, 0.f, 0.f, 0.f);
  float4 b1 = make_float4(0.f, 0.f, 0.f, 0.f);
  if constexpr (HASBIAS) {
    b0 = *(const float4*)&bias[tx * 4];
    if constexpr (JW == 2) b1 = *(const float4*)&bias[64 + tx * 4];
  }
#pragma unroll
  for (int i = 0; i < 8; ++i) {
    const int r = row0 + ty * 8 + i;
    {
      const int c = tx * 4;
      float4 o = make_float4(acc[i][0] + b0.x, acc[i][1] + b0.y,
                             acc[i][2] + b0.z, acc[i][3] + b0.w);
      if constexpr (RESID_XPOS) {
        float4 xv = *(const float4*)&xres[(size_t)r * 128 + c];
        float4 pv = *(const float4*)&pos[(r & 1023) * 128 + c];
        o.x += xv.x + pv.x; o.y += xv.y + pv.y;
        o.z += xv.z + pv.z; o.w += xv.w + pv.w;
      }
      if constexpr (RESID_PTR) {
        float4 rv = *(const float4*)&resid[(size_t)r * 128 + c];
        o.x += rv.x; o.y += rv.y; o.z += rv.z; o.w += rv.w;
      }
      if constexpr (RELU) {
        o.x = fmaxf(o.x, 0.f); o.y = fmaxf(o.y, 0.f);
        o.z = fmaxf(o.z, 0.f); o.w = fmaxf(o.w, 0.f);
      }
      *(float4*)&out[(size_t)r * NCOL + c] = o;
    }
    if constexpr (JW == 2) {
      const int c = 64 + tx * 4;
      float4 o = make_float4(acc[i][4] + b1.x, acc[i][5] + b1.y,
                             acc[i][6] + b1.z, acc[i][7] + b1.w);
      if constexpr (RESID_XPOS) {
        float4 xv = *(const float4*)&xres[(size_t)r * 128 + c];
        float4 pv = *(const float4*)&pos[(r & 1023) * 128 + c];
        o.x += xv.x + pv.x; o.y += xv.y + pv.y;
        o.z += xv.z + pv.z; o.w += xv.w + pv.w;
      }
      if constexpr (RESID_PTR) {
        float4 rv = *(const float4*)&resid[(size_t)r * 128 + c];
        o.x += rv.x; o.y += rv.y; o.z += rv.z; o.w += rv.w;
      }
      if constexpr (RELU) {
        o.x = fmaxf(o.x, 0.f); o.y = fmaxf(o.y, 0.f);
        o.z = fmaxf(o.z, 0.f); o.w = fmaxf(o.w, 0.f);
      }
      *(float4*)&out[(size_t)r * NCOL + c] = o;
    }
  }
}

// ---------------- top-16 per (bt, m) over 1024 scores ----------------
// S: [RTOT][64] row-major (scores, col = m). block = (bt, mg of 8 m's)
__global__ __launch_bounds__(256) void topk_kernel(
    const float* __restrict__ S, int* __restrict__ idx_out) {
  __shared__ float sc[8 * 1024];   // 32 KB
  const int tid = threadIdx.x;
  const int bt = blockIdx.x >> 3, mg = blockIdx.x & 7;
#pragma unroll
  for (int u = 0; u < 8; ++u) {
    int f = tid + 256 * u;         // < 2048
    int n = f >> 1, half = f & 1;
    float4 v = *(const float4*)&S[((size_t)bt * 1024 + n) * 64 + mg * 8 + half * 4];
    sc[(half * 4 + 0) * 1024 + n] = v.x;
    sc[(half * 4 + 1) * 1024 + n] = v.y;
    sc[(half * 4 + 2) * 1024 + n] = v.z;
    sc[(half * 4 + 3) * 1024 + n] = v.w;
  }
  __syncthreads();
  const int lane = tid & 63, w = tid >> 6;
  for (int ml = w * 2; ml < w * 2 + 2; ++ml) {
    float v[16];
#pragma unroll
    for (int q = 0; q < 4; ++q) {
      float4 t = *(const float4*)&sc[ml * 1024 + lane * 16 + q * 4];
      v[q * 4 + 0] = t.x; v[q * 4 + 1] = t.y;
      v[q * 4 + 2] = t.z; v[q * 4 + 3] = t.w;
    }
    const int outbase = (bt * 64 + mg * 8 + ml) << 4;
    for (int it = 0; it < 16; ++it) {
      float mv = v[0]; int li = 0;
#pragma unroll
      for (int u = 1; u < 16; ++u) {
        if (v[u] > mv) { mv = v[u]; li = u; }
      }
      int mi = (lane << 4) + li;
#pragma unroll
      for (int off = 1; off < 64; off <<= 1) {
        float ov = __shfl_xor(mv, off);
        int oi = __shfl_xor(mi, off);
        if (ov > mv || (ov == mv && oi < mi)) { mv = ov; mi = oi; }
      }
      // remove winner (tie-break matches jax: larger value, then smaller idx)
      bool mine = (mi >> 4) == lane;
      int rm = mi & 15;
#pragma unroll
      for (int u = 0; u < 16; ++u)
        if (mine && rm == u) v[u] = -3.402823466e38f;
      if (lane == 0) idx_out[outbase + it] = mi;
    }
  }
}

// ---------------- 16x16 attention, dense output (no scatter) ----------------
__global__ __launch_bounds__(256) void attn_dense(
    const float* __restrict__ Q, const float* __restrict__ K,
    const float* __restrict__ V, const int* __restrict__ idx,
    float* __restrict__ node_new) {
  __shared__ float sQ[16 * 132], sK[16 * 132], sV[16 * 132];
  __shared__ float sP[16 * 16];
  __shared__ int sidx[16];
  const int tid = threadIdx.x;
  const int bt = blockIdx.x >> 6, m = blockIdx.x & 63;
  if (tid < 16) sidx[tid] = idx[((bt * 64 + m) << 4) + tid];
  __syncthreads();
  const size_t base = (size_t)bt * 1024 * 128;
  // gather 3 x 16 rows of 128
#pragma unroll
  for (int u = 0; u < 6; ++u) {
    int f = tid + 256 * u;         // < 1536
    int mat = f >> 9;
    int r = (f >> 5) & 15;
    int c4 = (f & 31) << 2;
    const float* src = (mat == 0) ? Q : (mat == 1) ? K : V;
    float* dst = (mat == 0) ? sQ : (mat == 1) ? sK : sV;
    *(float4*)&dst[r * 132 + c4] =
        *(const float4*)&src[base + (size_t)sidx[r] * 128 + c4];
  }
  __syncthreads();
  // scores S[k][j] and softmax over j (16-lane groups)
  const int kk = tid >> 4, jj = tid & 15;
  float s = 0.f;
#pragma unroll
  for (int c4 = 0; c4 < 128; c4 += 4) {
    float4 q = *(const float4*)&sQ[kk * 132 + c4];
    float4 kv = *(const float4*)&sK[jj * 132 + c4];
    s = fmaf(q.x, kv.x, s); s = fmaf(q.y, kv.y, s);
    s = fmaf(q.z, kv.z, s); s = fmaf(q.w, kv.w, s);
  }
  s *= 0.08838834764831845f;       // 1/sqrt(128)
  float mx = s;
#pragma unroll
  for (int off = 8; off >= 1; off >>= 1) mx = fmaxf(mx, __shfl_xor(mx, off, 16));
  float e = expf(s - mx);
  float sum = e;
#pragma unroll
  for (int off = 8; off >= 1; off >>= 1) sum += __shfl_xor(sum, off, 16);
  sP[kk * 16 + jj] = e / sum;
  __syncthreads();
  // PV: row kk, col-group dc (8 cols each) -> dense store
  const int dc = tid & 15;
  const int d0 = dc * 8;
  float o[8] = {0.f, 0.f, 0.f, 0.f, 0.f, 0.f, 0.f, 0.f};
#pragma unroll
  for (int j = 0; j < 16; ++j) {
    float p = sP[kk * 16 + j];
    float4 v0 = *(const float4*)&sV[j * 132 + d0];
    float4 v1 = *(const float4*)&sV[j * 132 + d0 + 4];
    o[0] = fmaf(p, v0.x, o[0]); o[1] = fmaf(p, v0.y, o[1]);
    o[2] = fmaf(p, v0.z, o[2]); o[3] = fmaf(p, v0.w, o[3]);
    o[4] = fmaf(p, v1.x, o[4]); o[5] = fmaf(p, v1.y, o[5]);
    o[6] = fmaf(p, v1.z, o[6]); o[7] = fmaf(p, v1.w, o[7]);
  }
  float* orow = node_new + base + (size_t)(m * 16 + kk) * 128 + d0;
  *(float4*)&orow[0] = make_float4(o[0], o[1], o[2], o[3]);
  *(float4*)&orow[4] = make_float4(o[4], o[5], o[6], o[7]);
}

// ---------------- invert idx_flat into per-node hit lists ----------------
__global__ __launch_bounds__(256) void build_lists(
    const int* __restrict__ idx, int* __restrict__ lists,
    int* __restrict__ counts) {
  int i = blockIdx.x * 256 + threadIdx.x;      // < 192*1024
  int bt = i >> 10, j = i & 1023;
  int n = idx[i];
  int slot = atomicAdd(&counts[bt * 1024 + n], 1);
  lists[(size_t)(bt * 1024 + n) * 64 + slot] = j;
}

// ---------------- gather-sum: dict[bt][n] = sum(node_new rows)/cnt ----------
__global__ __launch_bounds__(256) void gather_sum(
    const float* __restrict__ node_new, const int* __restrict__ lists,
    const int* __restrict__ counts, float* __restrict__ out) {
  const int lane = threadIdx.x & 63;
  const int row = blockIdx.x * 4 + (threadIdx.x >> 6);   // bt*1024+n
  const int cnt = counts[row];
  const int bt = row >> 10;
  const float inv = 1.0f / ((float)cnt + 1e-14f);
  const int* lp = lists + (size_t)row * 64;
  float2 acc = make_float2(0.f, 0.f);
  for (int j = 0; j < cnt; ++j) {
    int src = lp[j];
    float2 v = *(const float2*)&node_new[((size_t)bt * 1024 + src) * 128 + lane * 2];
    acc.x += v.x; acc.y += v.y;
  }
  acc.x *= inv; acc.y *= inv;
  *(float2*)&out[(size_t)row * 128 + lane * 2] = acc;
}

// ---------------- LayerNorm over D=128, one wave per row ----------------
__global__ __launch_bounds__(256) void ln_kernel(
    const float* __restrict__ in, float* __restrict__ out) {
  const int lane = threadIdx.x & 63;
  const int row = blockIdx.x * 4 + (threadIdx.x >> 6);
  const float* p = in + (size_t)row * 128;
  float2 v = *(const float2*)&p[lane * 2];
  float s = v.x + v.y;
#pragma unroll
  for (int off = 32; off >= 1; off >>= 1) s += __shfl_xor(s, off);
  float mu = s * (1.f / 128.f);
  float dx = v.x - mu, dy = v.y - mu;
  float q = dx * dx + dy * dy;
#pragma unroll
  for (int off = 32; off >= 1; off >>= 1) q += __shfl_xor(q, off);
  float rstd = rsqrtf(q * (1.f / 128.f) + 1e-5f);
  float2 o = make_float2(dx * rstd, dy * rstd);
  *(float2*)&out[(size_t)row * 128 + lane * 2] = o;
}

// ---------------- launch ----------------
extern "C" void kernel_launch(void* const* d_in, const int* in_sizes, int n_in,
                              void* d_out, int out_size, void* d_ws, size_t ws_size,
                              hipStream_t stream) {
  const float* x      = (const float*)d_in[0];
  const float* eigvec = (const float*)d_in[1];
  const float* eigval = (const float*)d_in[2];
  const float* Wq     = (const float*)d_in[3];
  const float* bq     = (const float*)d_in[4];
  const float* Wk     = (const float*)d_in[5];
  const float* bk     = (const float*)d_in[6];
  const float* Wv     = (const float*)d_in[7];
  const float* bv     = (const float*)d_in[8];
  const float* Wo     = (const float*)d_in[9];
  const float* bo     = (const float*)d_in[10];
  const float* nemb   = (const float*)d_in[11];
  const float* ffW1   = (const float*)d_in[12];
  const float* ffb1   = (const float*)d_in[13];
  const float* ffW2   = (const float*)d_in[14];
  const float* ffb2   = (const float*)d_in[15];
  float* outp = (float*)d_out;

  char* ws = (char*)d_ws;
  const size_t SZ_MAT = (size_t)RTOT * 128 * 4;    // 100,663,296 B
  float* pos    = (float*)(ws + 0);                // 512 KB
  float* embT   = (float*)(ws + 524288);           // 64 KB
  int*   idxp   = (int*)  (ws + 589824);           // 768 KB
  int*   counts = (int*)  (ws + 1376256);          // 768 KB
  float* R1 = (float*)(ws + 2162688);              // K -> value_pre -> h1
  float* R2 = (float*)(ws + 2162688 + SZ_MAT);     // V -> lists -> value -> h2
  float* R3 = (float*)(ws + 2162688 + 2 * SZ_MAT); // scores -> node_new -> vln
  int* lists = (int*)R2;     // 50 MB, live only between build_lists/gather_sum
  float* Qbuf = outp;        // Q lives in d_out until attn_dense is done

  pos_kernel<<<512, 256, 0, stream>>>(eigvec, eigval, pos);
  embT_kernel<<<64, 256, 0, stream>>>(nemb, embT);

  // Q, K, V = (x + pos) @ W + b
  gemm_k<128, 2, 1, 0, 0, 0, 1><<<1536, 256, 0, stream>>>(
      x, nullptr, Wq, bq, pos, nullptr, nullptr, Qbuf);
  gemm_k<128, 2, 1, 0, 0, 0, 1><<<1536, 256, 0, stream>>>(
      x, nullptr, Wk, bk, pos, nullptr, nullptr, R1);
  gemm_k<128, 2, 1, 0, 0, 0, 1><<<1536, 256, 0, stream>>>(
      x, nullptr, Wv, bv, pos, nullptr, nullptr, R2);

  // scores[n][m] = concat(Q,K)[n] . node_emb[m]  (softmax skipped: monotone)
  gemm_k<64, 4, 0, 0, 0, 0, 0><<<1536, 256, 0, stream>>>(
      Qbuf, R1, embT, nullptr, nullptr, nullptr, nullptr, R3);
  topk_kernel<<<1536, 256, 0, stream>>>(R3, idxp);

  // dense 16x16 attention per (bt, m): node_new = softmax(QK^T/sqrtD) V
  attn_dense<<<12288, 256, 0, stream>>>(Qbuf, R1, R2, idxp, R3);

  // invert the index map, then gather-sum + normalize (V in R2 is dead now)
  hipMemsetAsync(counts, 0, (size_t)NBT * NNODE * 4, stream);
  build_lists<<<768, 256, 0, stream>>>(idxp, lists, counts);
  gather_sum<<<49152, 256, 0, stream>>>(R3, lists, counts, R1);

  // value = dictnorm @ Wo + bo + (x + pos); then LN
  gemm_k<128, 2, 0, 1, 0, 0, 1><<<1536, 256, 0, stream>>>(
      R1, nullptr, Wo, bo, pos, x, nullptr, R2);
  ln_kernel<<<49152, 256, 0, stream>>>(R2, R3);   // R3 = vln

  // FFN: h = relu(vln@W1+b1)@W2+b2 + vln; out = LN(h)
  gemm_k<128, 2, 0, 0, 0, 1, 1><<<1536, 256, 0, stream>>>(
      R3, nullptr, ffW1, ffb1, nullptr, nullptr, nullptr, R1);
  gemm_k<128, 2, 0, 0, 1, 0, 1><<<1536, 256, 0, stream>>>(
      R1, nullptr, ffW2, ffb2, nullptr, nullptr, R3, R2);
  ln_kernel<<<49152, 256, 0, stream>>>(R2, outp);
}

// Round 3
// 849.886 us; speedup vs baseline: 2.0215x; 1.2970x over previous
//
#include <hip/hip_runtime.h>
#include <math.h>

#define RTOT   196608   // B*T*N rows
#define NNODE  1024
#define NBT    192      // B*T

typedef __attribute__((ext_vector_type(8))) short short8;
typedef __attribute__((ext_vector_type(4))) float f32x4;

__device__ __forceinline__ unsigned short f2bf(float f) {
  unsigned u = __float_as_uint(f);
  return (unsigned short)((u + 0x7fffu + ((u >> 16) & 1u)) >> 16);
}
__device__ __forceinline__ float bf2f(unsigned short b) {
  return __uint_as_float(((unsigned)b) << 16);
}

// ---------------- prep kernels ----------------
__global__ __launch_bounds__(256) void pos_kernel(
    const float* __restrict__ eigvec, const float* __restrict__ eigval,
    float* __restrict__ pos) {
  int i = blockIdx.x * 256 + threadIdx.x;      // < 1024*128
  int d = i >> 10, n = i & 1023;
  pos[n * 128 + d] = eigvec[d * 1024 + n] * eigval[d];
}

__global__ __launch_bounds__(256) void embT_kernel(
    const float* __restrict__ emb, float* __restrict__ embT) {
  int i = blockIdx.x * 256 + threadIdx.x;      // < 64*256
  int m = i >> 8, k = i & 255;
  embT[k * 64 + m] = emb[i];
}

// transpose + bf16-ify 4 [128][128] weights -> [w][col][k] bf16
__global__ __launch_bounds__(256) void prepw_kernel(
    const float* __restrict__ W0, const float* __restrict__ W1,
    const float* __restrict__ W2, const float* __restrict__ W3,
    unsigned short* __restrict__ out) {
  int i = blockIdx.x * 256 + threadIdx.x;      // < 4*16384
  int wsel = i >> 14, rem = i & 16383, c = rem >> 7, k = rem & 127;
  const float* W = (wsel == 0) ? W0 : (wsel == 1) ? W1 : (wsel == 2) ? W2 : W3;
  out[i] = f2bf(W[k * 128 + c]);
}

// ---------------- generic 128-row-tile fp32 GEMM (score-critical path) ------
template<int NCOL, int KCHUNKS, int ADDPOS, int HASBIAS, int WRITEXB>
__global__ __launch_bounds__(256, 2) void gemm_k(
    const float* __restrict__ A1, const float* __restrict__ A2,
    const float* __restrict__ W, const float* __restrict__ bias,
    const float* __restrict__ pos, unsigned short* __restrict__ xb,
    float* __restrict__ out) {
  __shared__ float As[128 * 64];          // [m][k], 32 KB
  __shared__ float Ws[64 * NCOL];
  constexpr int JW = (NCOL == 128) ? 2 : 1;
  const int tid = threadIdx.x;
  const int tx = tid & 15, ty = tid >> 4;
  const int row0 = blockIdx.x * 128;

  float acc[8][4 * JW];
#pragma unroll
  for (int i = 0; i < 8; ++i)
#pragma unroll
    for (int j = 0; j < 4 * JW; ++j) acc[i][j] = 0.f;

  for (int kc = 0; kc < KCHUNKS; ++kc) {
    const int kt = kc * 64;
    const float* __restrict__ Asrc = (kt < 128) ? A1 : A2;
    const int kbase = kt & 127;
#pragma unroll
    for (int i = 0; i < 8; ++i) {
      int f = tid + 256 * i;
      int m = f >> 4;
      int k4 = (f & 15) << 2;
      int r = row0 + m;
      float4 a = *(const float4*)&Asrc[(size_t)r * 128 + kbase + k4];
      if constexpr (ADDPOS) {
        float4 p = *(const float4*)&pos[(r & 1023) * 128 + kbase + k4];
        a.x += p.x; a.y += p.y; a.z += p.z; a.w += p.w;
      }
      if constexpr (WRITEXB) {
        unsigned lo = (unsigned)f2bf(a.x) | ((unsigned)f2bf(a.y) << 16);
        unsigned hi = (unsigned)f2bf(a.z) | ((unsigned)f2bf(a.w) << 16);
        *(uint2*)&xb[(size_t)r * 128 + kbase + k4] = make_uint2(lo, hi);
      }
      *(float4*)&As[m * 64 + k4] = a;
    }
#pragma unroll
    for (int i = 0; i < NCOL / 16; ++i) {
      int f = tid + 256 * i;
      int kk = f / (NCOL / 4);
      int c4 = (f % (NCOL / 4)) << 2;
      *(float4*)&Ws[kk * NCOL + c4] =
          *(const float4*)&W[(size_t)(kt + kk) * NCOL + c4];
    }
    __syncthreads();
    for (int k4 = 0; k4 < 64; k4 += 4) {
      float a[8][4];
#pragma unroll
      for (int i = 0; i < 8; ++i)
        *(float4*)&a[i][0] = *(const float4*)&As[(ty * 8 + i) * 64 + k4];
#pragma unroll
      for (int kk = 0; kk < 4; ++kk) {
        float4 w0 = *(const float4*)&Ws[(k4 + kk) * NCOL + tx * 4];
        float4 w1;
        if constexpr (JW == 2)
          w1 = *(const float4*)&Ws[(k4 + kk) * NCOL + 64 + tx * 4];
#pragma unroll
        for (int i = 0; i < 8; ++i) {
          float av = a[i][kk];
          acc[i][0] = fmaf(av, w0.x, acc[i][0]);
          acc[i][1] = fmaf(av, w0.y, acc[i][1]);
          acc[i][2] = fmaf(av, w0.z, acc[i][2]);
          acc[i][3] = fmaf(av, w0.w, acc[i][3]);
          if constexpr (JW == 2) {
            acc[i][4] = fmaf(av, w1.x, acc[i][4]);
            acc[i][5] = fmaf(av, w1.y, acc[i][5]);
            acc[i][6] = fmaf(av, w1.z, acc[i][6]);
            acc[i][7] = fmaf(av, w1.w, acc[i][7]);
          }
        }
      }
    }
    __syncthreads();
  }
  float4 b0 = make_float4(0.f, 0.f, 0.f, 0.f);
  float4 b1 = make_float4(0.f, 0.f, 0.f, 0.f);
  if constexpr (HASBIAS) {
    b0 = *(const float4*)&bias[tx * 4];
    if constexpr (JW == 2) b1 = *(const float4*)&bias[64 + tx * 4];
  }
#pragma unroll
  for (int i = 0; i < 8; ++i) {
    const int r = row0 + ty * 8 + i;
    {
      float4 o = make_float4(acc[i][0] + b0.x, acc[i][1] + b0.y,
                             acc[i][2] + b0.z, acc[i][3] + b0.w);
      *(float4*)&out[(size_t)r * NCOL + tx * 4] = o;
    }
    if constexpr (JW == 2) {
      float4 o = make_float4(acc[i][4] + b1.x, acc[i][5] + b1.y,
                             acc[i][6] + b1.z, acc[i][7] + b1.w);
      *(float4*)&out[(size_t)r * NCOL + 64 + tx * 4] = o;
    }
  }
}

// ---------------- bf16 MFMA GEMM, 128x128 tile, K=128 -----------------------
// EPI: 0 = bias, fp32 out (V)
//      1 = bias + (x+pos) resid + LN, bf16 out (Wo -> vln)
//      2 = bias + relu, bf16 out (FF1 -> h1)
//      3 = bias + bf16 resid + LN, fp32 out (FF2 -> final)
template<int EPI>
__global__ __launch_bounds__(256, 2) void gemm_mfma(
    const unsigned short* __restrict__ A, const unsigned short* __restrict__ Bt,
    const float* __restrict__ bias, const float* __restrict__ x,
    const float* __restrict__ pos, const unsigned short* __restrict__ resb,
    float* __restrict__ outf, unsigned short* __restrict__ outb) {
  __shared__ float lds_s[128][2];
  __shared__ float lds_q[128][2];
  const int tid = threadIdx.x;
  const int w = tid >> 6, lane = tid & 63;
  const int wr = w >> 1, wc = w & 1;
  const int lhi = lane >> 4, llo = lane & 15;
  const int r0 = blockIdx.x * 128;

  // hold all B fragments for this wave's 64 cols (K=128): 64 VGPRs
  short8 bf[4][4];
#pragma unroll
  for (int j = 0; j < 4; ++j)
#pragma unroll
    for (int kq = 0; kq < 4; ++kq)
      bf[j][kq] = *(const short8*)&Bt[(size_t)(wc * 64 + j * 16 + llo) * 128 +
                                      kq * 32 + lhi * 8];
  f32x4 acc[4][4];
#pragma unroll
  for (int i = 0; i < 4; ++i)
#pragma unroll
    for (int j = 0; j < 4; ++j) acc[i][j] = (f32x4)(0.0f);

#pragma unroll
  for (int i = 0; i < 4; ++i) {
    short8 af[4];
#pragma unroll
    for (int kq = 0; kq < 4; ++kq)
      af[kq] = *(const short8*)&A[(size_t)(r0 + wr * 64 + i * 16 + llo) * 128 +
                                  kq * 32 + lhi * 8];
#pragma unroll
    for (int kq = 0; kq < 4; ++kq)
#pragma unroll
      for (int j = 0; j < 4; ++j)
        acc[i][j] = __builtin_amdgcn_mfma_f32_16x16x32_bf16(
            af[kq], bf[j][kq], acc[i][j], 0, 0, 0);
  }

  float bvals[4];
#pragma unroll
  for (int j = 0; j < 4; ++j) bvals[j] = bias[wc * 64 + j * 16 + llo];

  if constexpr (EPI == 1 || EPI == 3) {
#pragma unroll
    for (int i = 0; i < 4; ++i) {
#pragma unroll
      for (int reg = 0; reg < 4; ++reg) {
        const int rl = wr * 64 + i * 16 + lhi * 4 + reg;
        const int r = r0 + rl;
        float s = 0.f, q = 0.f;
#pragma unroll
        for (int j = 0; j < 4; ++j) {
          const int c = wc * 64 + j * 16 + llo;
          float vv = acc[i][j][reg] + bvals[j];
          if constexpr (EPI == 1)
            vv += x[(size_t)r * 128 + c] + pos[(r & 1023) * 128 + c];
          else
            vv += bf2f(resb[(size_t)r * 128 + c]);
          acc[i][j][reg] = vv;
          s += vv; q += vv * vv;
        }
#pragma unroll
        for (int m = 1; m < 16; m <<= 1) {
          s += __shfl_xor(s, m);
          q += __shfl_xor(q, m);
        }
        if (llo == 0) { lds_s[rl][wc] = s; lds_q[rl][wc] = q; }
      }
    }
    __syncthreads();
#pragma unroll
    for (int i = 0; i < 4; ++i) {
#pragma unroll
      for (int reg = 0; reg < 4; ++reg) {
        const int rl = wr * 64 + i * 16 + lhi * 4 + reg;
        const int r = r0 + rl;
        float s = lds_s[rl][0] + lds_s[rl][1];
        float q = lds_q[rl][0] + lds_q[rl][1];
        float mu = s * (1.f / 128.f);
        float rstd = rsqrtf(q * (1.f / 128.f) - mu * mu + 1e-5f);
#pragma unroll
        for (int j = 0; j < 4; ++j) {
          const int c = wc * 64 + j * 16 + llo;
          float vv = (acc[i][j][reg] - mu) * rstd;
          if constexpr (EPI == 1)
            outb[(size_t)r * 128 + c] = f2bf(vv);
          else
            outf[(size_t)r * 128 + c] = vv;
        }
      }
    }
  } else {
#pragma unroll
    for (int i = 0; i < 4; ++i)
#pragma unroll
      for (int reg = 0; reg < 4; ++reg) {
        const int rl = wr * 64 + i * 16 + lhi * 4 + reg;
        const int r = r0 + rl;
#pragma unroll
        for (int j = 0; j < 4; ++j) {
          const int c = wc * 64 + j * 16 + llo;
          float vv = acc[i][j][reg] + bvals[j];
          if constexpr (EPI == 2) {
            vv = fmaxf(vv, 0.f);
            outb[(size_t)r * 128 + c] = f2bf(vv);
          } else {
            outf[(size_t)r * 128 + c] = vv;
          }
        }
      }
  }
}

// ---------------- top-16 per (bt, m) over 1024 scores ----------------
__global__ __launch_bounds__(256) void topk_kernel(
    const float* __restrict__ S, int* __restrict__ idx_out) {
  __shared__ float sc[8 * 1024];   // 32 KB
  const int tid = threadIdx.x;
  const int bt = blockIdx.x >> 3, mg = blockIdx.x & 7;
#pragma unroll
  for (int u = 0; u < 8; ++u) {
    int f = tid + 256 * u;         // < 2048
    int n = f >> 1, half = f & 1;
    float4 v = *(const float4*)&S[((size_t)bt * 1024 + n) * 64 + mg * 8 + half * 4];
    sc[(half * 4 + 0) * 1024 + n] = v.x;
    sc[(half * 4 + 1) * 1024 + n] = v.y;
    sc[(half * 4 + 2) * 1024 + n] = v.z;
    sc[(half * 4 + 3) * 1024 + n] = v.w;
  }
  __syncthreads();
  const int lane = tid & 63, w = tid >> 6;
  for (int ml = w * 2; ml < w * 2 + 2; ++ml) {
    float v[16];
#pragma unroll
    for (int q = 0; q < 4; ++q) {
      float4 t = *(const float4*)&sc[ml * 1024 + lane * 16 + q * 4];
      v[q * 4 + 0] = t.x; v[q * 4 + 1] = t.y;
      v[q * 4 + 2] = t.z; v[q * 4 + 3] = t.w;
    }
    const int outbase = (bt * 64 + mg * 8 + ml) << 4;
    for (int it = 0; it < 16; ++it) {
      float mv = v[0]; int li = 0;
#pragma unroll
      for (int u = 1; u < 16; ++u) {
        if (v[u] > mv) { mv = v[u]; li = u; }
      }
      int mi = (lane << 4) + li;
#pragma unroll
      for (int off = 1; off < 64; off <<= 1) {
        float ov = __shfl_xor(mv, off);
        int oi = __shfl_xor(mi, off);
        if (ov > mv || (ov == mv && oi < mi)) { mv = ov; mi = oi; }
      }
      bool mine = (mi >> 4) == lane;
      int rm = mi & 15;
#pragma unroll
      for (int u = 0; u < 16; ++u)
        if (mine && rm == u) v[u] = -3.402823466e38f;
      if (lane == 0) idx_out[outbase + it] = mi;
    }
  }
}

// ---------------- 16x16 attention, dense bf16 output ----------------
__global__ __launch_bounds__(256) void attn_dense(
    const float* __restrict__ Q, const float* __restrict__ K,
    const float* __restrict__ V, const int* __restrict__ idx,
    unsigned short* __restrict__ node_new) {
  __shared__ float sQ[16 * 132], sK[16 * 132], sV[16 * 132];
  __shared__ float sP[16 * 16];
  __shared__ int sidx[16];
  const int tid = threadIdx.x;
  const int bt = blockIdx.x >> 6, m = blockIdx.x & 63;
  if (tid < 16) sidx[tid] = idx[((bt * 64 + m) << 4) + tid];
  __syncthreads();
  const size_t base = (size_t)bt * 1024 * 128;
#pragma unroll
  for (int u = 0; u < 6; ++u) {
    int f = tid + 256 * u;         // < 1536
    int mat = f >> 9;
    int r = (f >> 5) & 15;
    int c4 = (f & 31) << 2;
    const float* src = (mat == 0) ? Q : (mat == 1) ? K : V;
    float* dst = (mat == 0) ? sQ : (mat == 1) ? sK : sV;
    *(float4*)&dst[r * 132 + c4] =
        *(const float4*)&src[base + (size_t)sidx[r] * 128 + c4];
  }
  __syncthreads();
  const int kk = tid >> 4, jj = tid & 15;
  float s = 0.f;
#pragma unroll
  for (int c4 = 0; c4 < 128; c4 += 4) {
    float4 q = *(const float4*)&sQ[kk * 132 + c4];
    float4 kv = *(const float4*)&sK[jj * 132 + c4];
    s = fmaf(q.x, kv.x, s); s = fmaf(q.y, kv.y, s);
    s = fmaf(q.z, kv.z, s); s = fmaf(q.w, kv.w, s);
  }
  s *= 0.08838834764831845f;       // 1/sqrt(128)
  float mx = s;
#pragma unroll
  for (int off = 8; off >= 1; off >>= 1) mx = fmaxf(mx, __shfl_xor(mx, off, 16));
  float e = expf(s - mx);
  float sum = e;
#pragma unroll
  for (int off = 8; off >= 1; off >>= 1) sum += __shfl_xor(sum, off, 16);
  sP[kk * 16 + jj] = e / sum;
  __syncthreads();
  const int dc = tid & 15;
  const int d0 = dc * 8;
  float o[8] = {0.f, 0.f, 0.f, 0.f, 0.f, 0.f, 0.f, 0.f};
#pragma unroll
  for (int j = 0; j < 16; ++j) {
    float p = sP[kk * 16 + j];
    float4 v0 = *(const float4*)&sV[j * 132 + d0];
    float4 v1 = *(const float4*)&sV[j * 132 + d0 + 4];
    o[0] = fmaf(p, v0.x, o[0]); o[1] = fmaf(p, v0.y, o[1]);
    o[2] = fmaf(p, v0.z, o[2]); o[3] = fmaf(p, v0.w, o[3]);
    o[4] = fmaf(p, v1.x, o[4]); o[5] = fmaf(p, v1.y, o[5]);
    o[6] = fmaf(p, v1.z, o[6]); o[7] = fmaf(p, v1.w, o[7]);
  }
  unsigned short* orow = node_new + base + (size_t)(m * 16 + kk) * 128 + d0;
  uint4 st;
  st.x = (unsigned)f2bf(o[0]) | ((unsigned)f2bf(o[1]) << 16);
  st.y = (unsigned)f2bf(o[2]) | ((unsigned)f2bf(o[3]) << 16);
  st.z = (unsigned)f2bf(o[4]) | ((unsigned)f2bf(o[5]) << 16);
  st.w = (unsigned)f2bf(o[6]) | ((unsigned)f2bf(o[7]) << 16);
  *(uint4*)orow = st;
}

// ---------------- invert idx_flat into per-node hit lists ----------------
__global__ __launch_bounds__(256) void build_lists(
    const int* __restrict__ idx, int* __restrict__ lists,
    int* __restrict__ counts) {
  int i = blockIdx.x * 256 + threadIdx.x;      // < 192*1024
  int bt = i >> 10, j = i & 1023;
  int n = idx[i];
  int slot = atomicAdd(&counts[bt * 1024 + n], 1);
  lists[(size_t)(bt * 1024 + n) * 64 + slot] = j;
}

// ---------------- gather-sum: dictb[bt][n] = bf16(sum(rows)/cnt) ------------
__global__ __launch_bounds__(256) void gather_sum(
    const unsigned short* __restrict__ node_new, const int* __restrict__ lists,
    const int* __restrict__ counts, unsigned short* __restrict__ outb) {
  const int lane = threadIdx.x & 63;
  const int row = blockIdx.x * 4 + (threadIdx.x >> 6);   // bt*1024+n
  const int cnt = counts[row];
  const int bt = row >> 10;
  const float inv = 1.0f / ((float)cnt + 1e-14f);
  const int* lp = lists + (size_t)row * 64;
  float ax = 0.f, ay = 0.f;
  for (int j = 0; j < cnt; ++j) {
    int src = lp[j];
    unsigned u = *(const unsigned*)&node_new[((size_t)bt * 1024 + src) * 128 + lane * 2];
    ax += bf2f(u & 0xffff); ay += bf2f(u >> 16);
  }
  ax *= inv; ay *= inv;
  unsigned pk = (unsigned)f2bf(ax) | ((unsigned)f2bf(ay) << 16);
  *(unsigned*)&outb[(size_t)row * 128 + lane * 2] = pk;
}

// ---------------- launch ----------------
extern "C" void kernel_launch(void* const* d_in, const int* in_sizes, int n_in,
                              void* d_out, int out_size, void* d_ws, size_t ws_size,
                              hipStream_t stream) {
  const float* x      = (const float*)d_in[0];
  const float* eigvec = (const float*)d_in[1];
  const float* eigval = (const float*)d_in[2];
  const float* Wq     = (const float*)d_in[3];
  const float* bq     = (const float*)d_in[4];
  const float* Wk     = (const float*)d_in[5];
  const float* bk     = (const float*)d_in[6];
  const float* Wv     = (const float*)d_in[7];
  const float* bv     = (const float*)d_in[8];
  const float* Wo     = (const float*)d_in[9];
  const float* bo     = (const float*)d_in[10];
  const float* nemb   = (const float*)d_in[11];
  const float* ffW1   = (const float*)d_in[12];
  const float* ffb1   = (const float*)d_in[13];
  const float* ffW2   = (const float*)d_in[14];
  const float* ffb2   = (const float*)d_in[15];
  float* outp = (float*)d_out;

  char* ws = (char*)d_ws;
  const size_t SZ_MAT  = (size_t)RTOT * 128 * 4;   // 100,663,296
  const size_t SZ_BF   = (size_t)RTOT * 128 * 2;   //  50,331,648
  float*          pos    = (float*)(ws + 0);                  // 512 KB
  float*          embT   = (float*)(ws + 524288);             // 64 KB
  int*            idxp   = (int*)  (ws + 589824);             // 768 KB
  int*            counts = (int*)  (ws + 1376256);            // 768 KB
  unsigned short* Wtall  = (unsigned short*)(ws + 2162688);   // 128 KB (Wv,Wo,W1,W2 ^T bf16)
  unsigned short* xb     = (unsigned short*)(ws + 2293760);   // 48 MB: bf16(x+pos) -> vln
  float*          R1     = (float*)(ws + 52625408);           // 96 MB: K fp32 -> h1 bf16
  float*          R2     = (float*)(ws + 153288704);          // 96 MB: V fp32 -> lists
  float*          Sbuf   = (float*)(ws + 253952000);          // 48 MB: scores -> node_new bf16
  unsigned short* Wt_v = Wtall;
  unsigned short* Wt_o = Wtall + 16384;
  unsigned short* Wt_1 = Wtall + 32768;
  unsigned short* Wt_2 = Wtall + 49152;
  unsigned short* vln  = xb;                    // reuses xb after V-GEMM
  unsigned short* h1   = (unsigned short*)R1;   // reuses K after attn
  int*            lists = (int*)R2;             // reuses V after attn
  unsigned short* nnb  = (unsigned short*)Sbuf; // node_new bf16, after topk
  float*          Qbuf = outp;                  // Q in d_out until attn done
  unsigned short* dictb = (unsigned short*)d_out; // after gather (Q dead)

  pos_kernel<<<512, 256, 0, stream>>>(eigvec, eigval, pos);
  embT_kernel<<<64, 256, 0, stream>>>(nemb, embT);
  prepw_kernel<<<256, 256, 0, stream>>>(Wv, Wo, ffW1, ffW2, Wtall);

  // Q, K fp32 (score-critical); Q also emits bf16(x+pos)
  gemm_k<128, 2, 1, 1, 1><<<1536, 256, 0, stream>>>(
      x, nullptr, Wq, bq, pos, xb, Qbuf);
  gemm_k<128, 2, 1, 1, 0><<<1536, 256, 0, stream>>>(
      x, nullptr, Wk, bk, pos, nullptr, R1);
  // V via bf16 MFMA
  gemm_mfma<0><<<1536, 256, 0, stream>>>(
      xb, Wt_v, bv, nullptr, nullptr, nullptr, R2, nullptr);

  // scores = concat(Q,K) @ embT  (fp32; softmax monotone -> skipped)
  gemm_k<64, 4, 0, 0, 0><<<1536, 256, 0, stream>>>(
      Qbuf, R1, embT, nullptr, nullptr, nullptr, Sbuf);
  topk_kernel<<<1536, 256, 0, stream>>>(Sbuf, idxp);

  // dense 16x16 attention per (bt, m) -> node_new bf16 (over dead scores)
  attn_dense<<<12288, 256, 0, stream>>>(Qbuf, R1, R2, idxp, nnb);

  hipMemsetAsync(counts, 0, (size_t)NBT * NNODE * 4, stream);
  build_lists<<<768, 256, 0, stream>>>(idxp, lists, counts);
  gather_sum<<<49152, 256, 0, stream>>>(nnb, lists, counts, dictb);

  // value = dictb @ Wo + bo + (x+pos); LN fused -> vln bf16
  gemm_mfma<1><<<1536, 256, 0, stream>>>(
      dictb, Wt_o, bo, x, pos, nullptr, nullptr, vln);
  // h1 = relu(vln @ W1 + b1) bf16
  gemm_mfma<2><<<1536, 256, 0, stream>>>(
      vln, Wt_1, ffb1, nullptr, nullptr, nullptr, nullptr, h1);
  // out = LN(h1 @ W2 + b2 + vln) fp32
  gemm_mfma<3><<<1536, 256, 0, stream>>>(
      h1, Wt_2, ffb2, nullptr, nullptr, vln, outp, nullptr);
}